// Round 1
// baseline (108.091 us; speedup 1.0000x reference)
//
#include <hip/hip_runtime.h>
#include <math.h>

#define NB 2
#define NTOK 16384
#define CDIM 64
#define WIMG 128
#define NKV 256
#define NHEAD 8
#define HDIM 8
#define KTOT 4096
#define KSPLIT 16
#define RTOKS 512  // NB*NKV reduced tokens

// softmax scale folded with log2(e) so we can use native exp2
constexpr float KSCALE = 0.35355339059327373f * 1.4426950408889634f;

__device__ __forceinline__ float wave_reduce_sum64(float v) {
  #pragma unroll
  for (int off = 32; off > 0; off >>= 1) v += __shfl_xor(v, off, 64);
  return v;
}

// ---------------- K0: transpose conv weight [O][I][8][8] -> W2T[kk][o], kk = pos*64+i
__global__ __launch_bounds__(256) void k0_transpose_w(const float* __restrict__ srw,
                                                      float* __restrict__ w2t) {
  int idx = blockIdx.x * 256 + threadIdx.x;   // 262144 total
  int kk = idx >> 6;
  int o  = idx & 63;
  int pos = kk >> 6;
  int i   = kk & 63;
  w2t[idx] = srw[(o << 12) + (i << 6) + pos];
}

// ---------------- K1: conv as K-split GEMM. grid (16 token tiles, 16 k-chunks)
__global__ __launch_bounds__(256) void k1_conv_partial(const float* __restrict__ x,
                                                       const float* __restrict__ w2t,
                                                       float* __restrict__ pbuf) {
  __shared__ float xs[32][68];
  __shared__ float ws[64][68];
  const int t = threadIdx.x;
  const int tile = blockIdx.x;   // 0..15
  const int kch  = blockIdx.y;   // 0..15
  // loading indices
  const int lr = t >> 3, li0 = (t & 7) << 3;     // x: 32 rows x 64
  const int tgL = tile * 32 + lr;
  const int bL  = tgL >> 8;
  const int pL  = tgL & 255;
  const int phL = pL >> 4, pwL = pL & 15;
  const int wr = t >> 2, wo0 = (t & 3) << 4;     // w: 64 rows x 64
  // compute indices
  const int tokl = t >> 3;
  const int ob   = (t & 7) << 3;
  float acc[8];
  #pragma unroll
  for (int j = 0; j < 8; ++j) acc[j] = 0.f;

  for (int sc = 0; sc < 4; ++sc) {
    const int k0  = kch * 256 + sc * 64;   // 64-aligned chunk == one conv tap position
    const int pos = k0 >> 6;
    const int kh = pos >> 3, kw = pos & 7;
    const int nrow = (phL * 8 + kh) * WIMG + (pwL * 8 + kw);
    const float* xsrc = x + ((size_t)bL * NTOK + nrow) * CDIM + li0;
    float4 a0 = *(const float4*)(xsrc);
    float4 a1 = *(const float4*)(xsrc + 4);
    const float* wsrc = w2t + (size_t)(k0 + wr) * 64 + wo0;
    float4 b0 = *(const float4*)(wsrc);
    float4 b1 = *(const float4*)(wsrc + 4);
    float4 b2 = *(const float4*)(wsrc + 8);
    float4 b3 = *(const float4*)(wsrc + 12);
    __syncthreads();   // previous compute done before overwriting LDS
    *(float4*)&xs[lr][li0]     = a0;
    *(float4*)&xs[lr][li0 + 4] = a1;
    *(float4*)&ws[wr][wo0]      = b0;
    *(float4*)&ws[wr][wo0 + 4]  = b1;
    *(float4*)&ws[wr][wo0 + 8]  = b2;
    *(float4*)&ws[wr][wo0 + 12] = b3;
    __syncthreads();
    #pragma unroll 16
    for (int kk2 = 0; kk2 < 64; ++kk2) {
      const float xv = xs[tokl][kk2];
      #pragma unroll
      for (int j = 0; j < 8; ++j) acc[j] += xv * ws[kk2][ob + j];
    }
  }
  const int tg = tile * 32 + tokl;
  float* dst = pbuf + ((size_t)kch * RTOKS + tg) * 64 + ob;
  #pragma unroll
  for (int j = 0; j < 8; ++j) dst[j] = acc[j];
}

// ---------------- K2: reduce partials + bias + layernorm + KV projection
__global__ __launch_bounds__(64) void k2_ln_kv(const float* __restrict__ pbuf,
                                               const float* __restrict__ srb,
                                               const float* __restrict__ lng,
                                               const float* __restrict__ lnb,
                                               const float* __restrict__ kvw,
                                               float* __restrict__ kbuf,
                                               float* __restrict__ vbuf) {
  __shared__ float ylds[64];
  const int tg = blockIdx.x;    // 0..511 reduced token
  const int o  = threadIdx.x;   // 0..63 channel
  float y = srb[o];
  #pragma unroll
  for (int s = 0; s < KSPLIT; ++s) y += pbuf[((size_t)s * RTOKS + tg) * 64 + o];
  const float sum   = wave_reduce_sum64(y);
  const float sumsq = wave_reduce_sum64(y * y);
  const float mu  = sum * (1.f / 64.f);
  const float var = sumsq * (1.f / 64.f) - mu * mu;
  const float rstd = rsqrtf(var + 1e-5f);
  const float yn = (y - mu) * rstd * lng[o] + lnb[o];
  ylds[o] = yn;
  __syncthreads();
  float ka = 0.f, va = 0.f;
  #pragma unroll 16
  for (int i = 0; i < 64; ++i) {
    const float yv = ylds[i];
    ka += yv * kvw[i * 128 + o];
    va += yv * kvw[i * 128 + 64 + o];
  }
  const int b = tg >> 8, p = tg & 255;
  const int h = o >> 3, d = o & 7;
  const size_t idx = (((size_t)b * NHEAD + h) * NKV + p) * HDIM + d;
  kbuf[idx] = ka * KSCALE;   // fold softmax scale * log2e into K
  vbuf[idx] = va;
}

// ---------------- K3: q = x @ q_w, stored head-major [B][H][N][8]
__global__ __launch_bounds__(256) void k3_qproj(const float* __restrict__ x,
                                                const float* __restrict__ qw,
                                                float* __restrict__ qbuf) {
  __shared__ float xs[64][68];
  __shared__ float wsq[64][68];
  const int t = threadIdx.x;
  const int blk = blockIdx.x;          // 0..511
  const int b = blk >> 8;
  const int tok0 = (blk & 255) * 64;
  const int lr = t >> 2, lc0 = (t & 3) << 4;
  {
    const float* src = x + ((size_t)b * NTOK + tok0 + lr) * CDIM + lc0;
    float4 v0 = *(const float4*)(src);
    float4 v1 = *(const float4*)(src + 4);
    float4 v2 = *(const float4*)(src + 8);
    float4 v3 = *(const float4*)(src + 12);
    *(float4*)&xs[lr][lc0]      = v0;
    *(float4*)&xs[lr][lc0 + 4]  = v1;
    *(float4*)&xs[lr][lc0 + 8]  = v2;
    *(float4*)&xs[lr][lc0 + 12] = v3;
    const float* wsrc = qw + lr * 64 + lc0;
    float4 w0 = *(const float4*)(wsrc);
    float4 w1 = *(const float4*)(wsrc + 4);
    float4 w2 = *(const float4*)(wsrc + 8);
    float4 w3 = *(const float4*)(wsrc + 12);
    *(float4*)&wsq[lr][lc0]      = w0;
    *(float4*)&wsq[lr][lc0 + 4]  = w1;
    *(float4*)&wsq[lr][lc0 + 8]  = w2;
    *(float4*)&wsq[lr][lc0 + 12] = w3;
  }
  __syncthreads();
  const int tok = t >> 2, cb = (t & 3) << 4;
  float acc[16];
  #pragma unroll
  for (int j = 0; j < 16; ++j) acc[j] = 0.f;
  #pragma unroll 16
  for (int c = 0; c < 64; ++c) {
    const float xv = xs[tok][c];
    #pragma unroll
    for (int j = 0; j < 16; ++j) acc[j] += xv * wsq[c][cb + j];
  }
  const int tokg = tok0 + tok;
  #pragma unroll
  for (int g = 0; g < 2; ++g) {
    const int h = (cb >> 3) + g;
    float* dst = qbuf + (((size_t)b * NHEAD + h) * NTOK + tokg) * HDIM;
    float4 w0 = make_float4(acc[g*8+0], acc[g*8+1], acc[g*8+2], acc[g*8+3]);
    float4 w1 = make_float4(acc[g*8+4], acc[g*8+5], acc[g*8+6], acc[g*8+7]);
    *(float4*)(dst)     = w0;
    *(float4*)(dst + 4) = w1;
  }
}

// ---------------- K4: attention, 2 query tokens per thread, K/V in LDS (broadcast reads)
__global__ __launch_bounds__(256) void k4_attn(const float* __restrict__ qbuf,
                                               const float* __restrict__ kbuf,
                                               const float* __restrict__ vbuf,
                                               float* __restrict__ abuf) {
  __shared__ float kl[NKV][12];
  __shared__ float vl[NKV][12];
  const int t = threadIdx.x;
  const int tile = blockIdx.x;   // 32 tiles of 512 tokens
  const int h = blockIdx.y;
  const int b = blockIdx.z;
  const size_t bh = (size_t)b * NHEAD + h;
  {
    const float* ks = kbuf + (bh * NKV + t) * HDIM;
    const float* vs = vbuf + (bh * NKV + t) * HDIM;
    float4 k0 = *(const float4*)ks;
    float4 k1 = *(const float4*)(ks + 4);
    float4 v0 = *(const float4*)vs;
    float4 v1 = *(const float4*)(vs + 4);
    *(float4*)&kl[t][0] = k0;
    *(float4*)&kl[t][4] = k1;
    *(float4*)&vl[t][0] = v0;
    *(float4*)&vl[t][4] = v1;
  }
  const int tokA = tile * 512 + t;
  const int tokB = tokA + 256;
  const float* qap = qbuf + (bh * NTOK + tokA) * HDIM;
  const float* qbp = qbuf + (bh * NTOK + tokB) * HDIM;
  const float4 qa0 = *(const float4*)qap;
  const float4 qa1 = *(const float4*)(qap + 4);
  const float4 qb0 = *(const float4*)qbp;
  const float4 qb1 = *(const float4*)(qbp + 4);
  __syncthreads();

  float4 accA0 = make_float4(0,0,0,0), accA1 = make_float4(0,0,0,0);
  float4 accB0 = make_float4(0,0,0,0), accB1 = make_float4(0,0,0,0);
  float la = 0.f, lb = 0.f;
  #pragma unroll 4
  for (int j = 0; j < NKV; ++j) {
    const float4 k0 = *(const float4*)&kl[j][0];
    const float4 k1 = *(const float4*)&kl[j][4];
    const float sA = ((qa0.x*k0.x + qa0.y*k0.y) + (qa0.z*k0.z + qa0.w*k0.w))
                   + ((qa1.x*k1.x + qa1.y*k1.y) + (qa1.z*k1.z + qa1.w*k1.w));
    const float sB = ((qb0.x*k0.x + qb0.y*k0.y) + (qb0.z*k0.z + qb0.w*k0.w))
                   + ((qb1.x*k1.x + qb1.y*k1.y) + (qb1.z*k1.z + qb1.w*k1.w));
    const float eA = exp2f(sA);
    const float eB = exp2f(sB);
    la += eA; lb += eB;
    const float4 v0 = *(const float4*)&vl[j][0];
    const float4 v1 = *(const float4*)&vl[j][4];
    accA0.x += eA * v0.x; accA0.y += eA * v0.y; accA0.z += eA * v0.z; accA0.w += eA * v0.w;
    accA1.x += eA * v1.x; accA1.y += eA * v1.y; accA1.z += eA * v1.z; accA1.w += eA * v1.w;
    accB0.x += eB * v0.x; accB0.y += eB * v0.y; accB0.z += eB * v0.z; accB0.w += eB * v0.w;
    accB1.x += eB * v1.x; accB1.y += eB * v1.y; accB1.z += eB * v1.z; accB1.w += eB * v1.w;
  }
  const float ra = 1.0f / la;
  const float rb = 1.0f / lb;
  float* da = abuf + (bh * NTOK + tokA) * HDIM;
  float* db = abuf + (bh * NTOK + tokB) * HDIM;
  *(float4*)(da)     = make_float4(accA0.x*ra, accA0.y*ra, accA0.z*ra, accA0.w*ra);
  *(float4*)(da + 4) = make_float4(accA1.x*ra, accA1.y*ra, accA1.z*ra, accA1.w*ra);
  *(float4*)(db)     = make_float4(accB0.x*rb, accB0.y*rb, accB0.z*rb, accB0.w*rb);
  *(float4*)(db + 4) = make_float4(accB1.x*rb, accB1.y*rb, accB1.z*rb, accB1.w*rb);
}

// ---------------- K5: output projection + bias
__global__ __launch_bounds__(256) void k5_proj(const float* __restrict__ abuf,
                                               const float* __restrict__ pw,
                                               const float* __restrict__ pb,
                                               float* __restrict__ out) {
  __shared__ float as_[64][68];
  __shared__ float wsp[64][68];
  const int t = threadIdx.x;
  const int blk = blockIdx.x;  // 0..511
  const int b = blk >> 8;
  const int tok0 = (blk & 255) * 64;
  {
    // gather head-major attn-out into token-major LDS tile
    const int h = t >> 5;                    // 8 threads... t/32: head slice (512 floats each)
    const int rem = (t & 31) << 4;           // 0..496 within slice, 16 floats per thread
    const int tokL = rem >> 3;               // even token index, covers tokL, tokL+1
    const float* src = abuf + (((size_t)b * NHEAD + h) * NTOK + tok0 + tokL) * HDIM;
    float4 v0 = *(const float4*)(src);
    float4 v1 = *(const float4*)(src + 4);
    float4 v2 = *(const float4*)(src + 8);
    float4 v3 = *(const float4*)(src + 12);
    *(float4*)&as_[tokL][h * 8]         = v0;
    *(float4*)&as_[tokL][h * 8 + 4]     = v1;
    *(float4*)&as_[tokL + 1][h * 8]     = v2;
    *(float4*)&as_[tokL + 1][h * 8 + 4] = v3;
    const int wr = t >> 2, wc0 = (t & 3) << 4;
    const float* wsrc = pw + wr * 64 + wc0;
    float4 w0 = *(const float4*)(wsrc);
    float4 w1 = *(const float4*)(wsrc + 4);
    float4 w2 = *(const float4*)(wsrc + 8);
    float4 w3 = *(const float4*)(wsrc + 12);
    *(float4*)&wsp[wr][wc0]      = w0;
    *(float4*)&wsp[wr][wc0 + 4]  = w1;
    *(float4*)&wsp[wr][wc0 + 8]  = w2;
    *(float4*)&wsp[wr][wc0 + 12] = w3;
  }
  __syncthreads();
  const int tok = t >> 2, cb = (t & 3) << 4;
  float acc[16];
  #pragma unroll
  for (int j = 0; j < 16; ++j) acc[j] = 0.f;
  #pragma unroll 16
  for (int c = 0; c < 64; ++c) {
    const float xv = as_[tok][c];
    #pragma unroll
    for (int j = 0; j < 16; ++j) acc[j] += xv * wsp[c][cb + j];
  }
  float* dst = out + ((size_t)b * NTOK + tok0 + tok) * CDIM + cb;
  #pragma unroll
  for (int j = 0; j < 16; ++j) acc[j] += pb[cb + j];
  *(float4*)(dst)      = make_float4(acc[0], acc[1], acc[2], acc[3]);
  *(float4*)(dst + 4)  = make_float4(acc[4], acc[5], acc[6], acc[7]);
  *(float4*)(dst + 8)  = make_float4(acc[8], acc[9], acc[10], acc[11]);
  *(float4*)(dst + 12) = make_float4(acc[12], acc[13], acc[14], acc[15]);
}

extern "C" void kernel_launch(void* const* d_in, const int* in_sizes, int n_in,
                              void* d_out, int out_size, void* d_ws, size_t ws_size,
                              hipStream_t stream) {
  const float* x    = (const float*)d_in[0];
  // d_in[1], d_in[2] are H, W scalars (128, 128) — fixed by the problem
  const float* qw   = (const float*)d_in[3];
  const float* kvw  = (const float*)d_in[4];
  const float* srw  = (const float*)d_in[5];
  const float* srb  = (const float*)d_in[6];
  const float* lng  = (const float*)d_in[7];
  const float* lnb  = (const float*)d_in[8];
  const float* pw   = (const float*)d_in[9];
  const float* pb   = (const float*)d_in[10];
  float* out = (float*)d_out;
  float* ws  = (float*)d_ws;

  float* w2t  = ws;                 // 262144 floats (transposed conv weight)
  float* pbuf = ws + 262144;        // 524288 floats (conv K-split partials)
  float* kbuf = ws + 786432;        // 32768 floats
  float* vbuf = ws + 819200;        // 32768 floats
  float* qbuf = ws + 851968;        // 2097152 floats
  float* abuf = ws + 2949120;       // 2097152 floats

  k0_transpose_w<<<1024, 256, 0, stream>>>(srw, w2t);
  k1_conv_partial<<<dim3(16, 16), 256, 0, stream>>>(x, w2t, pbuf);
  k2_ln_kv<<<512, 64, 0, stream>>>(pbuf, srb, lng, lnb, kvw, kbuf, vbuf);
  k3_qproj<<<512, 256, 0, stream>>>(x, qw, qbuf);
  k4_attn<<<dim3(32, NHEAD, NB), 256, 0, stream>>>(qbuf, kbuf, vbuf, abuf);
  k5_proj<<<512, 256, 0, stream>>>(abuf, pw, pb, out);
}